// Round 9
// baseline (250.663 us; speedup 1.0000x reference)
//
#include <hip/hip_runtime.h>
#include <hip/hip_bf16.h>

#define E_    8
#define D_    2048
#define H_    1024
#define T_    2048   // B*L tokens
#define BK    64

using u16   = unsigned short;
using s16x8 = __attribute__((ext_vector_type(8))) short;
using f32x4 = __attribute__((ext_vector_type(4))) float;

#define WAITVM0 asm volatile("s_waitcnt vmcnt(0)" ::: "memory")

__device__ __forceinline__ short f2bf(float f) {
  __hip_bfloat16 h = __float2bfloat16(f);          // HW v_cvt (RNE)
  return __builtin_bit_cast(short, h);
}
// swizzled LDS slot (elem index) for (row, 8-elem chunk) in a [*][64] bf16 tile
__device__ __forceinline__ int slot(int r, int c) { return r * 64 + ((c ^ (r & 7)) << 3); }

__device__ __forceinline__ void gload16(const void* g, void* l) {
  __builtin_amdgcn_global_load_lds((const __attribute__((address_space(1))) void*)g,
                                   (__attribute__((address_space(3))) void*)l, 16, 0, 0);
}

// find (e, mt, Ne) for linear m-tile index ml (BM=256); registers only
#define FIND_EXPERT(ml, cnt, e, mt, Ne)                        \
  { int b_ = 0;                                                \
    _Pragma("unroll")                                          \
    for (int i_ = 0; i_ < E_; ++i_) {                          \
      int ti_ = (cnt[i_] + 255) >> 8;                          \
      if ((ml) >= b_ && (ml) < b_ + ti_) {                     \
        e = i_; mt = (ml) - b_; Ne = cnt[i_]; }                \
      b_ += ti_; } }

// ---------------- workspace layout (bytes) ----------------
// xb     : T*D bf16      =  8,388,608  @ 0
// a_buf  : E*T*H bf16    = 33,554,432  @ 8,388,608
// wb_in  : E*2H*D bf16   = 67,108,864  @ 41,943,040
// wb_out : E*D*H bf16    = 33,554,432  @ 109,051,904
// lists  : E*T int       =     65,536  @ 142,606,336
// gates  : T*K f32       =     16,384  @ 142,671,872
// counts : E int         =         32  @ 142,688,256

#define WIN_ELEMS  33554432   // E*2H*D
#define WOUT_ELEMS 16777216   // E*D*H

// high-ILP fp32->bf16 streaming convert: 4 independent 16B loads per iter
__global__ __launch_bounds__(256) void convert_kernel(
    const float* __restrict__ src, u16* __restrict__ dst, int n)
{
  int stride = gridDim.x * 256 * 16;
  for (int i = (blockIdx.x * 256 + threadIdx.x) * 16; i < n; i += stride) {
    f32x4 a0 = *(const f32x4*)(src + i);
    f32x4 a1 = *(const f32x4*)(src + i + 4);
    f32x4 a2 = *(const f32x4*)(src + i + 8);
    f32x4 a3 = *(const f32x4*)(src + i + 12);
    s16x8 o0, o1;
    o0[0]=f2bf(a0.x); o0[1]=f2bf(a0.y); o0[2]=f2bf(a0.z); o0[3]=f2bf(a0.w);
    o0[4]=f2bf(a1.x); o0[5]=f2bf(a1.y); o0[6]=f2bf(a1.z); o0[7]=f2bf(a1.w);
    o1[0]=f2bf(a2.x); o1[1]=f2bf(a2.y); o1[2]=f2bf(a2.z); o1[3]=f2bf(a2.w);
    o1[4]=f2bf(a3.x); o1[5]=f2bf(a3.y); o1[6]=f2bf(a3.z); o1[7]=f2bf(a3.w);
    *(s16x8*)(dst + i)     = o0;
    *(s16x8*)(dst + i + 8) = o1;
  }
}

// one block per token: logits, top-2 + softmax, lists, x -> bf16, out = bias
__global__ __launch_bounds__(256) void router_kernel(
    const float* __restrict__ x, const float* __restrict__ wg,
    const float* __restrict__ bias,
    u16* __restrict__ xb, int* __restrict__ lists, float* __restrict__ gates,
    int* __restrict__ counts, float* __restrict__ out)
{
  int t = blockIdx.x;
  int tid = threadIdx.x;

  {
    const float* bp = bias + tid * 8;
    f32x4 b0 = *(const f32x4*)(bp), b1 = *(const f32x4*)(bp + 4);
    *(f32x4*)(out + (size_t)t * D_ + tid * 8)     = b0;
    *(f32x4*)(out + (size_t)t * D_ + tid * 8 + 4) = b1;
    if (t == 0 && tid == 0) out[(size_t)T_ * D_] = 0.0f;   // router aux loss
  }

  const float* xr = x + (size_t)t * D_;
  float acc[E_];
#pragma unroll
  for (int e = 0; e < E_; ++e) acc[e] = 0.f;
#pragma unroll
  for (int i = 0; i < D_ / 256; ++i) {
    int d = tid + 256 * i;
    float xv = xr[d];
    xb[(size_t)t * D_ + d] = (u16)f2bf(xv);
#pragma unroll
    for (int e = 0; e < E_; ++e) acc[e] += xv * wg[e * D_ + d];
  }
#pragma unroll
  for (int off = 32; off >= 1; off >>= 1)
#pragma unroll
    for (int e = 0; e < E_; ++e) acc[e] += __shfl_down(acc[e], off);

  __shared__ float red[4][E_];
  int w = tid >> 6, lane = tid & 63;
  if (lane == 0)
#pragma unroll
    for (int e = 0; e < E_; ++e) red[w][e] = acc[e];
  __syncthreads();
  if (tid == 0) {
    float v0 = -1e30f, v1 = -1e30f; int e0 = 0, e1 = 0;
#pragma unroll
    for (int e = 0; e < E_; ++e) {
      float v = red[0][e] + red[1][e] + red[2][e] + red[3][e];
      if (v > v0)      { v1 = v0; e1 = e0; v0 = v; e0 = e; }
      else if (v > v1) { v1 = v;  e1 = e; }
    }
    float g1 = expf(v1 - v0);
    float inv = 1.f / (1.f + g1);
    float g0 = inv; g1 *= inv;
    int s0 = atomicAdd(&counts[e0], 1);
    lists[e0 * T_ + s0] = t * 2 + 0;
    gates[t * 2 + 0] = g0;
    int s1 = atomicAdd(&counts[e1], 1);
    lists[e1 * T_ + s1] = t * 2 + 1;
    gates[t * 2 + 1] = g1;
  }
}

// grouped GEMM1 + SiLU-GLU. BM=256 rows x 64 B-rows (32 h-cols: h1/h2 per 16).
// 8 waves (4m x 2n) of 64x32. Pair-interleaved tile order: m-tiles paired,
// n-major within pair, m fastest -> each B-slice read ~once per XCD.
__global__ __launch_bounds__(512, 2) void gemm1_kernel(
    const u16* __restrict__ xb, const u16* __restrict__ wb_in,
    const int* __restrict__ lists, const int* __restrict__ counts,
    u16* __restrict__ a_buf)
{
  __shared__ __align__(16) u16 As[2][256 * 64];   // 64 KB
  __shared__ __align__(16) u16 Bs[2][64 * 64];    // 16 KB -> 80 KB, 2 blocks/CU

  int cnt[E_];
#pragma unroll
  for (int i = 0; i < E_; ++i) cnt[i] = counts[i];
  int mt_total = 0;
#pragma unroll
  for (int i = 0; i < E_; ++i) mt_total += (cnt[i] + 255) >> 8;
  const int NN = 32;                              // n-tiles (32 h-cols each)
  int total_padded = ((mt_total + 1) >> 1) * (2 * NN);
  int chunk = (total_padded + 7) >> 3;

  int tid = threadIdx.x, w = tid >> 6, lane = tid & 63;
  int swzc = ((lane & 7) ^ (lane >> 3)) * 8;      // pre-swizzled source chunk
  int wr = (w >> 1) * 64, wc = (w & 1) * 32, lrow = lane & 15, g = lane >> 4;
  int lcol = lane & 15, lr4 = (lane >> 4) * 4;
  int xcd = blockIdx.x & 7, bslot = blockIdx.x >> 3;

  for (int sl = bslot; sl < chunk; sl += 64) {
    int u = xcd * chunk + sl;
    if (u >= total_padded) break;
    int p = u / (2 * NN), q = u % (2 * NN);
    int ml = p * 2 + (q & 1), n = q >> 1;         // m fastest within pair
    if (ml >= mt_total) continue;
    int e = 0, mt = 0, Ne = 0;
    FIND_EXPERT(ml, cnt, e, mt, Ne);

    const u16* ap[4];
#pragma unroll
    for (int i = 0; i < 4; ++i) {
      int gr = mt * 256 + w * 8 + i * 64 + (lane >> 3);
      if (gr >= Ne) gr = Ne - 1;
      ap[i] = xb + (size_t)(lists[e * T_ + gr] >> 1) * D_ + swzc;
    }
    // B row r (0..63) -> wb_in row: h-col n*32 + (r>>5)*16 + (r&15), mat (r>>4)&1
    const u16* bp;
    {
      int r = w * 8 + (lane >> 3);
      int o = n * 32 + ((r >> 4) & 1) * H_ + (r >> 5) * 16 + (r & 15);
      bp = wb_in + (size_t)e * (2 * H_) * D_ + (size_t)o * D_ + swzc;
    }

    f32x4 acc[4][2];
#pragma unroll
    for (int m = 0; m < 4; ++m) { acc[m][0] = (f32x4){0,0,0,0}; acc[m][1] = (f32x4){0,0,0,0}; }

    // prologue: stage kt=0 into buf 0 (5 gloads/thread)
#pragma unroll
    for (int i = 0; i < 4; ++i) gload16(ap[i], &As[0][(w * 8 + i * 64) * 64]);
    gload16(bp, &Bs[0][(w * 8) * 64]);
    WAITVM0;
    __syncthreads();

    const int NT = D_ / BK;                        // 32
    for (int kt = 0; kt < NT; ++kt) {
      int cur = kt & 1;
      if (kt + 1 < NT) {
        int k = (kt + 1) * BK;
#pragma unroll
        for (int i = 0; i < 4; ++i) gload16(ap[i] + k, &As[cur ^ 1][(w * 8 + i * 64) * 64]);
        gload16(bp + k, &Bs[cur ^ 1][(w * 8) * 64]);
      }
#pragma unroll
      for (int ks = 0; ks < 2; ++ks) {
        int ch = ks * 4 + g;
        s16x8 af[4], bf[2];
#pragma unroll
        for (int m = 0; m < 4; ++m) af[m] = *(const s16x8*)(&As[cur][slot(wr + m * 16 + lrow, ch)]);
#pragma unroll
        for (int s = 0; s < 2; ++s)  bf[s] = *(const s16x8*)(&Bs[cur][slot(wc + s * 16 + lrow, ch)]);
#pragma unroll
        for (int m = 0; m < 4; ++m)
#pragma unroll
          for (int s = 0; s < 2; ++s)
            acc[m][s] = __builtin_amdgcn_mfma_f32_16x16x32_bf16(af[m], bf[s], acc[m][s], 0, 0, 0);
      }
      WAITVM0;
      __syncthreads();
    }
    // epilogue: acc[m][0]=h1, acc[m][1]=h2 -> a = silu(h1)*h2
#pragma unroll
    for (int m = 0; m < 4; ++m)
#pragma unroll
      for (int qq = 0; qq < 4; ++qq) {
        int row = mt * 256 + wr + m * 16 + lr4 + qq;
        if (row < Ne) {
          float h1 = acc[m][0][qq], h2 = acc[m][1][qq];
          float a = (h1 / (1.f + __expf(-h1))) * h2;
          int col = n * 32 + (w & 1) * 16 + lcol;
          a_buf[((size_t)e * T_ + row) * H_ + col] = (u16)f2bf(a);
        }
      }
  }
}

// grouped GEMM2: out[t] += gate * (a_row . wb_out^T). BM=256 x 64 d-cols.
__global__ __launch_bounds__(512, 2) void gemm2_kernel(
    const u16* __restrict__ a_buf, const u16* __restrict__ wb_out,
    const int* __restrict__ lists, const int* __restrict__ counts,
    const float* __restrict__ gates, float* __restrict__ out)
{
  __shared__ __align__(16) u16 As[2][256 * 64];
  __shared__ __align__(16) u16 Bs[2][64 * 64];

  int cnt[E_];
#pragma unroll
  for (int i = 0; i < E_; ++i) cnt[i] = counts[i];
  int mt_total = 0;
#pragma unroll
  for (int i = 0; i < E_; ++i) mt_total += (cnt[i] + 255) >> 8;
  const int NN = 32;                              // n-tiles of 64 d-cols
  int total_padded = ((mt_total + 1) >> 1) * (2 * NN);
  int chunk = (total_padded + 7) >> 3;

  int tid = threadIdx.x, w = tid >> 6, lane = tid & 63;
  int swzc = ((lane & 7) ^ (lane >> 3)) * 8;
  int wr = (w >> 1) * 64, wc = (w & 1) * 32, lrow = lane & 15, g = lane >> 4;
  int lcol = lane & 15, lr4 = (lane >> 4) * 4;
  int xcd = blockIdx.x & 7, bslot = blockIdx.x >> 3;

  for (int sl = bslot; sl < chunk; sl += 64) {
    int u = xcd * chunk + sl;
    if (u >= total_padded) break;
    int p = u / (2 * NN), q = u % (2 * NN);
    int ml = p * 2 + (q & 1), n = q >> 1;
    if (ml >= mt_total) continue;
    int e = 0, mt = 0, Ne = 0;
    FIND_EXPERT(ml, cnt, e, mt, Ne);

    const u16* ap[4];
#pragma unroll
    for (int i = 0; i < 4; ++i) {
      int gr = mt * 256 + w * 8 + i * 64 + (lane >> 3);
      if (gr >= Ne) gr = Ne - 1;
      ap[i] = a_buf + ((size_t)e * T_ + gr) * H_ + swzc;
    }
    const u16* bp;
    {
      int r = w * 8 + (lane >> 3);
      bp = wb_out + (size_t)e * D_ * H_ + (size_t)(n * 64 + r) * H_ + swzc;
    }

    f32x4 acc[4][2];
#pragma unroll
    for (int m = 0; m < 4; ++m) { acc[m][0] = (f32x4){0,0,0,0}; acc[m][1] = (f32x4){0,0,0,0}; }

#pragma unroll
    for (int i = 0; i < 4; ++i) gload16(ap[i], &As[0][(w * 8 + i * 64) * 64]);
    gload16(bp, &Bs[0][(w * 8) * 64]);
    WAITVM0;
    __syncthreads();

    const int NT = H_ / BK;                        // 16
    for (int kt = 0; kt < NT; ++kt) {
      int cur = kt & 1;
      if (kt + 1 < NT) {
        int k = (kt + 1) * BK;
#pragma unroll
        for (int i = 0; i < 4; ++i) gload16(ap[i] + k, &As[cur ^ 1][(w * 8 + i * 64) * 64]);
        gload16(bp + k, &Bs[cur ^ 1][(w * 8) * 64]);
      }
#pragma unroll
      for (int ks = 0; ks < 2; ++ks) {
        int ch = ks * 4 + g;
        s16x8 af[4], bf[2];
#pragma unroll
        for (int m = 0; m < 4; ++m) af[m] = *(const s16x8*)(&As[cur][slot(wr + m * 16 + lrow, ch)]);
#pragma unroll
        for (int s = 0; s < 2; ++s)  bf[s] = *(const s16x8*)(&Bs[cur][slot(wc + s * 16 + lrow, ch)]);
#pragma unroll
        for (int m = 0; m < 4; ++m)
#pragma unroll
          for (int s = 0; s < 2; ++s)
            acc[m][s] = __builtin_amdgcn_mfma_f32_16x16x32_bf16(af[m], bf[s], acc[m][s], 0, 0, 0);
      }
      WAITVM0;
      __syncthreads();
    }
    // epilogue: atomic accumulate (bias pre-filled by router)
#pragma unroll
    for (int m = 0; m < 4; ++m)
#pragma unroll
      for (int qq = 0; qq < 4; ++qq) {
        int row = mt * 256 + wr + m * 16 + lr4 + qq;
        if (row < Ne) {
          int pp = lists[e * T_ + row];
          float gt = gates[pp];
          int tok = pp >> 1;
#pragma unroll
          for (int s = 0; s < 2; ++s)
            atomicAdd(&out[(size_t)tok * D_ + n * 64 + wc + s * 16 + lcol], gt * acc[m][s][qq]);
        }
      }
  }
}

extern "C" void kernel_launch(void* const* d_in, const int* in_sizes, int n_in,
                              void* d_out, int out_size, void* d_ws, size_t ws_size,
                              hipStream_t stream)
{
  const float* x      = (const float*)d_in[0];
  const float* w_gate = (const float*)d_in[1];
  const float* w_in   = (const float*)d_in[2];
  const float* w_out  = (const float*)d_in[3];
  const float* bias   = (const float*)d_in[4];
  float* out = (float*)d_out;

  char* ws = (char*)d_ws;
  u16*   xb     = (u16*)(ws);
  u16*   a_buf  = (u16*)(ws + 8388608);
  u16*   wb_in  = (u16*)(ws + 41943040);
  u16*   wb_out = (u16*)(ws + 109051904);
  int*   lists  = (int*)(ws + 142606336);
  float* gates  = (float*)(ws + 142671872);
  int*   counts = (int*)(ws + 142688256);

  hipMemsetAsync(counts, 0, E_ * sizeof(int), stream);
  convert_kernel<<<2048, 256, 0, stream>>>(w_in,  wb_in,  WIN_ELEMS);
  convert_kernel<<<2048, 256, 0, stream>>>(w_out, wb_out, WOUT_ELEMS);
  router_kernel<<<T_, 256, 0, stream>>>(x, w_gate, bias, xb, lists, gates, counts, out);
  gemm1_kernel<<<512, 512, 0, stream>>>(xb, wb_in, lists, counts, a_buf);
  gemm2_kernel<<<512, 512, 0, stream>>>(a_buf, wb_out, lists, counts, gates, out);
}